// Round 2
// baseline (213.409 us; speedup 1.0000x reference)
//
#include <hip/hip_runtime.h>

typedef short  bf16x8  __attribute__((ext_vector_type(8)));
typedef float  f32x4   __attribute__((ext_vector_type(4)));
typedef float  f32x16  __attribute__((ext_vector_type(16)));
typedef unsigned short ushort;

__device__ __forceinline__ short f2bf(float f) {
  __bf16 h = (__bf16)f;                 // RNE
  return __builtin_bit_cast(short, h);
}

// ws layout (float offsets):
//   [0        .. 4194304)  gate partials: ks*524288 + b*8192 + gate*2048 + j   (ks 0..7)
//   [4194304  .. 5242880)  y partials:    4194304 + ksy*131072 + b*2048 + j    (ksy 0..7)
//   [5242880  .. )         Abf: bf16 [64][4096] = 262144 ushorts (h | x concat)
#define GATE_PART 0
#define Y_PART    4194304
#define ABF_OFF   5242880

// ---------------------------------------------------------------------------
// Kernel 0: convert A = [h_prev | x] to bf16, row-major [64][4096].
// ---------------------------------------------------------------------------
__global__ __launch_bounds__(256) void lstm_aconv(
    const float* __restrict__ X, const float* __restrict__ H,
    ushort* __restrict__ Abf)
{
  const int t  = blockIdx.x * 256 + threadIdx.x;   // 32768 threads
  const int e0 = t * 8;                            // 8 elems/thread
  const int b  = e0 >> 12;
  const int k  = e0 & 4095;
  const float* src = (k < 2048) ? (H + (size_t)b * 2048 + k)
                                : (X + (size_t)b * 2048 + (k - 2048));
  f32x4 v0 = *(const f32x4*)(src);
  f32x4 v1 = *(const f32x4*)(src + 4);
  bf16x8 o;
  o[0] = f2bf(v0[0]); o[1] = f2bf(v0[1]); o[2] = f2bf(v0[2]); o[3] = f2bf(v0[3]);
  o[4] = f2bf(v1[0]); o[5] = f2bf(v1[1]); o[6] = f2bf(v1[2]); o[7] = f2bf(v1[3]);
  *(bf16x8*)(Abf + e0) = o;
}

// ---------------------------------------------------------------------------
// Per-wave skinny GEMM: C[64 x 32] += A[64 x K] * W[K x 32] over nsteps K=16
// steps, mfma_f32_32x32x16_bf16, no LDS, no barriers, 1-step SW pipeline.
// wbase = W + krow0*2048 + j0 + n (per-lane).  a0p/a1p = bf16 A rows.
// ---------------------------------------------------------------------------
__device__ __forceinline__ void gemm_wave(
    const float* __restrict__ wbase,
    const ushort* __restrict__ a0p, const ushort* __restrict__ a1p,
    int nsteps, float bias, float* __restrict__ outBase, int outStride,
    int lane)
{
  const int kg8 = (lane >> 5) << 3;   // k sub-group offset (0 or 8)

  f32x16 acc0, acc1;
  #pragma unroll
  for (int r = 0; r < 16; ++r) { acc0[r] = bias; acc1[r] = bias; }

  float wf[8]; bf16x8 a0, a1;
  {
    const float* p = wbase + (size_t)kg8 * 2048;
    #pragma unroll
    for (int i = 0; i < 8; ++i) wf[i] = p[(size_t)i * 2048];
    a0 = *(const bf16x8*)(a0p);
    a1 = *(const bf16x8*)(a1p);
  }

  for (int s = 0; s < nsteps - 1; ++s) {
    float wn[8]; bf16x8 a0n, a1n;
    {  // prefetch step s+1
      const float* p = wbase + (size_t)((s + 1) * 16 + kg8) * 2048;
      #pragma unroll
      for (int i = 0; i < 8; ++i) wn[i] = p[(size_t)i * 2048];
      a0n = *(const bf16x8*)(a0p + (s + 1) * 16);
      a1n = *(const bf16x8*)(a1p + (s + 1) * 16);
    }
    bf16x8 bf;
    #pragma unroll
    for (int i = 0; i < 8; ++i) bf[i] = f2bf(wf[i]);
    acc0 = __builtin_amdgcn_mfma_f32_32x32x16_bf16(a0, bf, acc0, 0, 0, 0);
    acc1 = __builtin_amdgcn_mfma_f32_32x32x16_bf16(a1, bf, acc1, 0, 0, 0);
    #pragma unroll
    for (int i = 0; i < 8; ++i) wf[i] = wn[i];
    a0 = a0n; a1 = a1n;
  }
  {  // last step
    bf16x8 bf;
    #pragma unroll
    for (int i = 0; i < 8; ++i) bf[i] = f2bf(wf[i]);
    acc0 = __builtin_amdgcn_mfma_f32_32x32x16_bf16(a0, bf, acc0, 0, 0, 0);
    acc1 = __builtin_amdgcn_mfma_f32_32x32x16_bf16(a1, bf, acc1, 0, 0, 0);
  }

  // D layout (32x32): col = lane&31, row = (r&3) + 8*(r>>2) + 4*(lane>>5)
  const int rbase = 4 * (lane >> 5);
  #pragma unroll
  for (int r = 0; r < 16; ++r) {
    const int row = (r & 3) + 8 * (r >> 2) + rbase;
    outBase[(size_t)row * outStride]        = acc0[r];
    outBase[(size_t)(row + 32) * outStride] = acc1[r];
  }
}

// ---------------------------------------------------------------------------
// Kernel 1: 2560 independent waves.
//   w < 2048 : gate job.  gate=w>>9, ks=(w>>6)&7, jt=w&63  (K=512, 32 steps)
//   w >= 2048: y job.     ksy=(w-2048)>>6, jt=(w-2048)&63  (K=256, 16 steps)
// ---------------------------------------------------------------------------
__global__ __launch_bounds__(256) void lstm_gemm(
    const float* __restrict__ Wfh, const float* __restrict__ Wfx, const float* __restrict__ bfp,
    const float* __restrict__ Wih, const float* __restrict__ Wix, const float* __restrict__ bip,
    const float* __restrict__ Woh, const float* __restrict__ Wox, const float* __restrict__ bop,
    const float* __restrict__ Wch, const float* __restrict__ Wcx, const float* __restrict__ bcp,
    const float* __restrict__ Wy,  const float* __restrict__ by,
    float* __restrict__ ws)
{
  const int lane = threadIdx.x & 63;
  const int w    = blockIdx.x * 4 + (threadIdx.x >> 6);
  const int n    = lane & 31;
  const ushort* Abf = (const ushort*)(ws + ABF_OFF);

  if (w < 2048) {
    const int gate = w >> 9;
    const int ks   = (w >> 6) & 7;
    const int jt   = w & 63;
    const int j0   = jt * 32;

    const float *Wg_h, *Wg_x, *bg;
    if      (gate == 0) { Wg_h = Wfh; Wg_x = Wfx; bg = bfp; }
    else if (gate == 1) { Wg_h = Wih; Wg_x = Wix; bg = bip; }
    else if (gate == 2) { Wg_h = Wch; Wg_x = Wcx; bg = bcp; }
    else                { Wg_h = Woh; Wg_x = Wox; bg = bop; }

    const float* Wmat = (ks < 4) ? Wg_h : Wg_x;
    const int krow0 = (ks & 3) * 512;          // row within that matrix
    const int aK0   = ks * 512;                // col in concat A (h:0..2047, x:2048..)
    const float bias = (ks == 0) ? bg[j0 + n] : 0.f;

    const float* wbase = Wmat + (size_t)krow0 * 2048 + j0 + n;
    const int kg8 = (lane >> 5) << 3;
    const ushort* a0p = Abf + (size_t)(lane & 31) * 4096 + aK0 + kg8;
    const ushort* a1p = a0p + (size_t)32 * 4096;
    float* outBase = ws + GATE_PART + (size_t)ks * 524288 + gate * 2048 + j0 + n;

    gemm_wave(wbase, a0p, a1p, 32, bias, outBase, 8192, lane);
  } else {
    const int yi  = w - 2048;
    const int ksy = yi >> 6;
    const int jt  = yi & 63;
    const int j0  = jt * 32;

    const int krow0 = ksy * 256;
    const float bias = (ksy == 0) ? by[j0 + n] : 0.f;

    const float* wbase = Wy + (size_t)krow0 * 2048 + j0 + n;
    const int kg8 = (lane >> 5) << 3;
    const ushort* a0p = Abf + (size_t)(lane & 31) * 4096 + krow0 + kg8;  // y uses h (k<2048)
    const ushort* a1p = a0p + (size_t)32 * 4096;
    float* outBase = ws + Y_PART + (size_t)ksy * 131072 + j0 + n;

    gemm_wave(wbase, a0p, a1p, 16, bias, outBase, 2048, lane);
  }
}

// ---------------------------------------------------------------------------
// Kernel 2: reduce K-split partials, apply LSTM nonlinearity, pack [y|h|c].
// ---------------------------------------------------------------------------
__global__ __launch_bounds__(64) void lstm_combine(
    const float* __restrict__ ws, const float* __restrict__ c_prev,
    float* __restrict__ out)
{
  const int t  = blockIdx.x * 64 + threadIdx.x;  // 0..32767
  const int b  = t >> 9;
  const int j4 = (t & 511) * 4;

  f32x4 g[4];
  #pragma unroll
  for (int gg = 0; gg < 4; ++gg) {
    f32x4 s = (f32x4){0.f, 0.f, 0.f, 0.f};
    #pragma unroll
    for (int ks = 0; ks < 8; ++ks)
      s += *(const f32x4*)(ws + GATE_PART + (size_t)ks * 524288 + (size_t)b * 8192 + gg * 2048 + j4);
    g[gg] = s;
  }
  f32x4 ysum = (f32x4){0.f, 0.f, 0.f, 0.f};
  #pragma unroll
  for (int ks = 0; ks < 8; ++ks)
    ysum += *(const f32x4*)(ws + Y_PART + (size_t)ks * 131072 + (size_t)b * 2048 + j4);

  const f32x4 cp = *(const f32x4*)(c_prev + (size_t)b * 2048 + j4);
  f32x4 hF, cF;
  #pragma unroll
  for (int e = 0; e < 4; ++e) {
    float f  = 1.f / (1.f + __expf(-g[0][e]));
    float i  = 1.f / (1.f + __expf(-g[1][e]));
    float ct = tanhf(g[2][e]);
    float o  = 1.f / (1.f + __expf(-g[3][e]));
    float c  = f * cp[e] + i * ct;
    cF[e] = c;
    hF[e] = o * tanhf(c);
  }
  float* ob = out + (size_t)b * 6144;
  *(f32x4*)(ob + j4)        = ysum;   // y = h_prev @ Wy + by
  *(f32x4*)(ob + 2048 + j4) = hF;     // h
  *(f32x4*)(ob + 4096 + j4) = cF;     // c
}

extern "C" void kernel_launch(void* const* d_in, const int* in_sizes, int n_in,
                              void* d_out, int out_size, void* d_ws, size_t ws_size,
                              hipStream_t stream)
{
  const float* X   = (const float*)d_in[0];
  const float* H   = (const float*)d_in[1];
  const float* Cp  = (const float*)d_in[2];
  const float* Wfh = (const float*)d_in[3];
  const float* Wfx = (const float*)d_in[4];
  const float* bfp = (const float*)d_in[5];
  const float* Wih = (const float*)d_in[6];
  const float* Wix = (const float*)d_in[7];
  const float* bip = (const float*)d_in[8];
  const float* Woh = (const float*)d_in[9];
  const float* Wox = (const float*)d_in[10];
  const float* bop = (const float*)d_in[11];
  const float* Wch = (const float*)d_in[12];
  const float* Wcx = (const float*)d_in[13];
  const float* bcp = (const float*)d_in[14];
  const float* Wy  = (const float*)d_in[15];
  const float* by  = (const float*)d_in[16];
  float* ws  = (float*)d_ws;
  float* out = (float*)d_out;

  lstm_aconv<<<128, 256, 0, stream>>>(X, H, (ushort*)(ws + ABF_OFF));
  lstm_gemm<<<640, 256, 0, stream>>>(Wfh, Wfx, bfp, Wih, Wix, bip,
                                     Woh, Wox, bop, Wch, Wcx, bcp, Wy, by, ws);
  lstm_combine<<<512, 64, 0, stream>>>(ws, Cp, out);
}